// Round 10
// baseline (315.276 us; speedup 1.0000x reference)
//
#include <hip/hip_runtime.h>

#define NE 8
#define TA 8192
#define MAXT 40
#define MAXPAD (MAXT*256)       // 10240

typedef __attribute__((ext_vector_type(4)))  float f32x4;
typedef __attribute__((ext_vector_type(16))) float f32x16;
typedef __attribute__((ext_vector_type(8)))  short s16x8;

// ws int-area layout (int indices)
#define WS_CUR  8    // [8]
#define WS_META 16   // [2] {ntiles256, total_padded}
#define WS_TEXP 18   // [<=40]
#define WS_PERM 256  // [MAXPAD]

#define WAITVM(N) asm volatile("s_waitcnt vmcnt(" #N ")" ::: "memory")
#define BAR()     asm volatile("s_barrier" ::: "memory")

__device__ __forceinline__ unsigned short f2bf(float f) {
  unsigned u = __builtin_bit_cast(unsigned, f);
  u += 0x7FFFu + ((u >> 16) & 1u);   // RNE (inputs finite)
  return (unsigned short)(u >> 16);
}

__device__ __forceinline__ void glds16(const unsigned short* g, unsigned short* l) {
  __builtin_amdgcn_global_load_lds(
      (const __attribute__((address_space(1))) unsigned int*)g,
      (__attribute__((address_space(3))) unsigned int*)l, 16, 0, 0);
}

// ---------------- routing: single kernel ----------------
__global__ void k_route(const int* __restrict__ idx, int* __restrict__ ws) {
  __shared__ int cnt[NE];
  int t = threadIdx.x;                 // 1024 threads, 1 block
  if (t < NE) cnt[t] = 0;
  __syncthreads();
  int e0[8];
#pragma unroll
  for (int k = 0; k < 8; ++k) { e0[k] = idx[t + k * 1024]; atomicAdd(&cnt[e0[k]], 1); }
  __syncthreads();
  if (t == 0) {
    int off = 0, ti = 0;
    for (int e = 0; e < NE; ++e) {
      ws[WS_CUR + e] = off;
      int c = cnt[e];
      int ntl = (c + 255) >> 8;
      for (int k = 0; k < ntl; ++k) ws[WS_TEXP + ti++] = e;
      off += ntl << 8;
    }
    ws[WS_META] = ti;
    ws[WS_META + 1] = off;
  }
#pragma unroll
  for (int k = 0; k < MAXPAD / 1024; ++k) ws[WS_PERM + t + k * 1024] = -1;
  __syncthreads();
#pragma unroll
  for (int k = 0; k < 8; ++k) {
    int p = atomicAdd(&ws[WS_CUR + e0[k]], 1);
    ws[WS_PERM + p] = t + k * 1024;
  }
}

// ---------------- fused gate+up convert, 32-row interleave ----------------
// dest row (per expert, 4096 rows): (h>>5)*64 + (h&31) gate, +32 up
__global__ void k_cvt_gu2(const float* __restrict__ g, const float* __restrict__ u,
                          unsigned short* __restrict__ d) {
  int t = blockIdx.x * 256 + threadIdx.x;
  int i = t * 8;
  int dd = i & 1023;
  int h = (i >> 10) & 2047;
  int e = i >> 21;
  int dr = (e << 12) + ((h >> 5) << 6) + (h & 31);
  f32x4 a = *(const f32x4*)(g + i);
  f32x4 b = *(const f32x4*)(g + i + 4);
  s16x8 o;
  o[0] = (short)f2bf(a[0]); o[1] = (short)f2bf(a[1]);
  o[2] = (short)f2bf(a[2]); o[3] = (short)f2bf(a[3]);
  o[4] = (short)f2bf(b[0]); o[5] = (short)f2bf(b[1]);
  o[6] = (short)f2bf(b[2]); o[7] = (short)f2bf(b[3]);
  *(s16x8*)(d + (size_t)dr * 1024 + dd) = o;
  a = *(const f32x4*)(u + i);
  b = *(const f32x4*)(u + i + 4);
  o[0] = (short)f2bf(a[0]); o[1] = (short)f2bf(a[1]);
  o[2] = (short)f2bf(a[2]); o[3] = (short)f2bf(a[3]);
  o[4] = (short)f2bf(b[0]); o[5] = (short)f2bf(b[1]);
  o[6] = (short)f2bf(b[2]); o[7] = (short)f2bf(b[3]);
  *(s16x8*)(d + (size_t)(dr + 32) * 1024 + dd) = o;
}

// ---------------- plain f32 -> bf16 (w_down) ----------------
__global__ void k_cvt(const float* __restrict__ s, unsigned short* __restrict__ d) {
  int i = (blockIdx.x * 256 + threadIdx.x) * 8;
  f32x4 a = *(const f32x4*)(s + i);
  f32x4 b = *(const f32x4*)(s + i + 4);
  s16x8 o;
  o[0] = (short)f2bf(a[0]); o[1] = (short)f2bf(a[1]);
  o[2] = (short)f2bf(a[2]); o[3] = (short)f2bf(a[3]);
  o[4] = (short)f2bf(b[0]); o[5] = (short)f2bf(b[1]);
  o[6] = (short)f2bf(b[2]); o[7] = (short)f2bf(b[3]);
  *(s16x8*)(d + i) = o;
}

// ---------------- gather x rows ----------------
__global__ void k_gather(const float* __restrict__ x, const int* __restrict__ ws,
                         unsigned short* __restrict__ xb) {
  int tid = blockIdx.x * 256 + threadIdx.x;
  int r = tid >> 7;
  int c = (tid & 127) << 3;
  int ta = ws[WS_PERM + r];
  s16x8 o = {0,0,0,0,0,0,0,0};
  if (ta >= 0) {
    const float* xp = x + (size_t)(ta >> 1) * 1024 + c;
    f32x4 a = *(const f32x4*)xp;
    f32x4 b = *(const f32x4*)(xp + 4);
    o[0] = (short)f2bf(a[0]); o[1] = (short)f2bf(a[1]);
    o[2] = (short)f2bf(a[2]); o[3] = (short)f2bf(a[3]);
    o[4] = (short)f2bf(b[0]); o[5] = (short)f2bf(b[1]);
    o[6] = (short)f2bf(b[2]); o[7] = (short)f2bf(b[3]);
  }
  *(s16x8*)(xb + (size_t)r * 1024 + c) = o;
}

// ================= 256x256 phase-spread GEMM =================
// 512 thr, 8 waves (2M x 4N). Wave out: 128 rows x 64 B-rows (g+u or 2 col-grps).
// 32x32x16 MFMA, 4 a-frag reuse. LDS [2][A 256x64 | B 256x64] = 128 KB, 1 blk/CU.
// K-tile = 64; 4 phases (1 kstep each), barrier-separated:
//   ph0: stage A(t+1) (4 glds) | ph1: stage B(t+1) (4 glds) | ph2,3: compute only.
// Boundary WAITVM(0) has ~2.5 phases of slack -> near-free.
// Swizzle: LDS row = 8 chunks x 8 elems; phys slot = chunk ^ (row&7); glds source
// pre-swizzled (R2-proven, 0 conflicts). Frag reads use slot ((2*ks+kg) ^ (r31&7)).

#define STG4(GPTR, LDST, KO, RSTRIDE)                                  \
  _Pragma("unroll")                                                    \
  for (int j = 0; j < 4; ++j)                                          \
    glds16((GPTR) + (size_t)j * 64 * (RSTRIDE) + (KO), (LDST) + j * 4096 + tid * 8);

#define PHASE(LC, KS, ACCX, ACCY, BO1)                                 \
  {                                                                    \
    int sc = (((KS) * 2 + kg) ^ x7) << 3;                              \
    s16x8 a0 = *(const s16x8*)&(LC)[aof + sc];                         \
    s16x8 a1 = *(const s16x8*)&(LC)[aof + 2048 + sc];                  \
    s16x8 a2 = *(const s16x8*)&(LC)[aof + 4096 + sc];                  \
    s16x8 a3 = *(const s16x8*)&(LC)[aof + 6144 + sc];                  \
    s16x8 bx = *(const s16x8*)&(LC)[bgo + sc];                         \
    s16x8 by = *(const s16x8*)&(LC)[bgo + (BO1) + sc];                 \
    __builtin_amdgcn_s_setprio(1);                                     \
    ACCX[0] = __builtin_amdgcn_mfma_f32_32x32x16_bf16(a0, bx, ACCX[0], 0, 0, 0); \
    ACCY[0] = __builtin_amdgcn_mfma_f32_32x32x16_bf16(a0, by, ACCY[0], 0, 0, 0); \
    ACCX[1] = __builtin_amdgcn_mfma_f32_32x32x16_bf16(a1, bx, ACCX[1], 0, 0, 0); \
    ACCY[1] = __builtin_amdgcn_mfma_f32_32x32x16_bf16(a1, by, ACCY[1], 0, 0, 0); \
    ACCX[2] = __builtin_amdgcn_mfma_f32_32x32x16_bf16(a2, bx, ACCX[2], 0, 0, 0); \
    ACCY[2] = __builtin_amdgcn_mfma_f32_32x32x16_bf16(a2, by, ACCY[2], 0, 0, 0); \
    ACCX[3] = __builtin_amdgcn_mfma_f32_32x32x16_bf16(a3, bx, ACCX[3], 0, 0, 0); \
    ACCY[3] = __builtin_amdgcn_mfma_f32_32x32x16_bf16(a3, by, ACCY[3], 0, 0, 0); \
    __builtin_amdgcn_s_setprio(0);                                     \
  }

#define GEOM                                                           \
  int tid = threadIdx.x, lane = tid & 63, wid = tid >> 6;              \
  int wm = wid >> 2, wn = wid & 3;                                     \
  int r31 = lane & 31, kg = lane >> 5, x7 = r31 & 7;                   \
  int srow = tid >> 3;                                                 \
  int cs = (tid & 7) ^ (srow & 7);                                     \
  int aof = (wm * 128 + r31) * 64;                                     \
  int bgo = 16384 + (wn * 64 + r31) * 64;

// ---------------- GEMM1: h = silu(x@Wg^T)*(x@Wu^T), fused ----------------
__global__ __launch_bounds__(512) void k_gemm1(
    const unsigned short* __restrict__ xb, const unsigned short* __restrict__ wgu,
    unsigned short* __restrict__ hb, const int* __restrict__ ws) {
  int mt = blockIdx.y;
  if (mt >= ws[WS_META]) return;
  int e = ws[WS_TEXP + mt];
  int nt = blockIdx.x;   // 0..15 (128 real h each)

  __shared__ unsigned short L[2][32768];

  GEOM

  const unsigned short* gA = xb  + (size_t)(mt * 256 + srow) * 1024 + cs * 8;
  const unsigned short* gB = wgu + (size_t)(e * 4096 + nt * 256 + srow) * 1024 + cs * 8;

  f32x16 accg[4] = {}, accu[4] = {};

  STG4(gA, &L[0][0],     0, 1024)
  STG4(gB, &L[0][16384], 0, 1024)

  for (int t = 0; t < 16; ++t) {
    const unsigned short* Lc = &L[t & 1][0];
    unsigned short* Ln = &L[(t & 1) ^ 1][0];
    int ko = (t + 1) * 64;
    WAITVM(0);
    BAR();
    if (t < 15) { STG4(gA, Ln, ko, 1024) }
    PHASE(Lc, 0, accg, accu, 2048)
    BAR();
    if (t < 15) { STG4(gB, Ln + 16384, ko, 1024) }
    PHASE(Lc, 1, accg, accu, 2048)
    BAR();
    PHASE(Lc, 2, accg, accu, 2048)
    BAR();
    PHASE(Lc, 3, accg, accu, 2048)
  }

  // epilogue: C 32x32: col=lane&31, row=(r&3)+8*(r>>2)+4*(lane>>5)
  int hrow0 = mt * 256 + wm * 128;
  int hcol  = nt * 128 + wn * 32 + r31;
#pragma unroll
  for (int mi = 0; mi < 4; ++mi)
#pragma unroll
    for (int r = 0; r < 16; ++r) {
      int crow = (r & 3) + 8 * (r >> 2) + 4 * kg;
      float g = accg[mi][r];
      float u = accu[mi][r];
      float h = (g / (1.f + __expf(-g))) * u;
      hb[(size_t)(hrow0 + mi * 32 + crow) * 2048 + hcol] = f2bf(h);
    }
}

// ---------------- GEMM2: out = h @ Wd^T, split-K=2, atomic scatter ----------------
__global__ __launch_bounds__(512) void k_gemm2(
    const unsigned short* __restrict__ hb, const unsigned short* __restrict__ wdb,
    float* __restrict__ out, const int* __restrict__ ws) {
  int mt = blockIdx.y;
  if (mt >= ws[WS_META]) return;
  int e = ws[WS_TEXP + mt];
  int nt = blockIdx.x & 3;            // 256 d-cols each
  int kb = (blockIdx.x >> 2) * 1024;  // split-K slice

  __shared__ unsigned short L[2][32768];

  GEOM

  const unsigned short* gA = hb  + (size_t)(mt * 256 + srow) * 2048 + kb + cs * 8;
  const unsigned short* gB = wdb + (size_t)(e * 1024 + nt * 256 + srow) * 2048 + kb + cs * 8;

  f32x16 acc0[4] = {}, acc1[4] = {};

  STG4(gA, &L[0][0],     0, 2048)
  STG4(gB, &L[0][16384], 0, 2048)

  for (int t = 0; t < 16; ++t) {
    const unsigned short* Lc = &L[t & 1][0];
    unsigned short* Ln = &L[(t & 1) ^ 1][0];
    int ko = (t + 1) * 64;
    WAITVM(0);
    BAR();
    if (t < 15) { STG4(gA, Ln, ko, 2048) }
    PHASE(Lc, 0, acc0, acc1, 2048)
    BAR();
    if (t < 15) { STG4(gB, Ln + 16384, ko, 2048) }
    PHASE(Lc, 1, acc0, acc1, 2048)
    BAR();
    PHASE(Lc, 2, acc0, acc1, 2048)
    BAR();
    PHASE(Lc, 3, acc0, acc1, 2048)
  }

  int prow0 = mt * 256 + wm * 128;
  int dcol  = nt * 256 + wn * 64 + r31;
#pragma unroll
  for (int mi = 0; mi < 4; ++mi)
#pragma unroll
    for (int r = 0; r < 16; ++r) {
      int crow = (r & 3) + 8 * (r >> 2) + 4 * kg;
      int ta = ws[WS_PERM + prow0 + mi * 32 + crow];
      if (ta >= 0) {
        unsafeAtomicAdd(&out[(size_t)ta * 1024 + dcol],      acc0[mi][r]);
        unsafeAtomicAdd(&out[(size_t)ta * 1024 + dcol + 32], acc1[mi][r]);
      }
    }
}

extern "C" void kernel_launch(void* const* d_in, const int* in_sizes, int n_in,
                              void* d_out, int out_size, void* d_ws, size_t ws_size,
                              hipStream_t stream) {
  const float* x   = (const float*)d_in[0];
  const int*   idx = (const int*)d_in[1];
  const float* wg  = (const float*)d_in[2];
  const float* wu  = (const float*)d_in[3];
  const float* wd  = (const float*)d_in[4];
  float* out = (float*)d_out;

  int*  wsi = (int*)d_ws;
  char* wsb = (char*)d_ws;
  // xb and wdb OVERLAY (xb dead after gemm1; cvt_wd runs after gemm1)
  const size_t OFF_XB  = 65536;
  const size_t OFF_WDB = 65536;
  const size_t OFF_WGU = 65536 + (size_t)NE * 1024 * 2048 * 2;
  const size_t OFF_HB  = OFF_WGU + (size_t)NE * 4096 * 1024 * 2;
  unsigned short* xbuf = (unsigned short*)(wsb + OFF_XB);
  unsigned short* wdb  = (unsigned short*)(wsb + OFF_WDB);
  unsigned short* wgu  = (unsigned short*)(wsb + OFF_WGU);
  unsigned short* hb   = (unsigned short*)(wsb + OFF_HB);

  k_route<<<1, 1024, 0, stream>>>(idx, wsi);
  k_cvt_gu2<<<(NE * 2048 * 1024) / (256 * 8), 256, 0, stream>>>(wg, wu, wgu);
  k_gather<<<(MAXPAD * 128) / 256, 256, 0, stream>>>(x, wsi, xbuf);

  k_gemm1<<<dim3(16, MAXT), 512, 0, stream>>>(xbuf, wgu, hb, wsi);

  k_cvt<<<(NE * 1024 * 2048) / (256 * 8), 256, 0, stream>>>(wd, wdb);   // overlay after gemm1

  hipMemsetAsync(out, 0, (size_t)out_size * sizeof(float), stream);     // atomics accumulate
  k_gemm2<<<dim3(8, MAXT), 512, 0, stream>>>(hb, wdb, out, wsi);
}